// Round 9
// baseline (847.134 us; speedup 1.0000x reference)
//
#include <hip/hip_runtime.h>
#include <hip/hip_bf16.h>

typedef __bf16 bf16_t;
typedef bf16_t bf16x8 __attribute__((ext_vector_type(8)));
typedef bf16_t bf16x4 __attribute__((ext_vector_type(4)));
typedef float  f32x4  __attribute__((ext_vector_type(4)));

#define BM 256
#define BN 128
#define BK 32            // one K-tile; a row is 4 chunks of 8 bf16 (16B each)
#define ABUF (BM * BK)   // 8192 elems
#define BBUF (BN * BK)   // 4096 elems

enum { EPI_NONE = 0, EPI_THRESH = 1, EPI_BIAS = 2 };

__device__ __forceinline__ void memfence() { asm volatile("" ::: "memory"); }
__device__ __forceinline__ void blockbar() {
    memfence(); __builtin_amdgcn_s_barrier(); memfence();
}

#define GLD16(src, dst) __builtin_amdgcn_global_load_lds( \
    (const __attribute__((address_space(1))) void*)(src), \
    (__attribute__((address_space(3))) void*)(dst), 16, 0, 0)

// 256x128 tile, BK=32, 512 threads = 8 waves (4M x 2N), per-wave C = 64x64.
// R6 measured: 2 blocks/CU (72 KiB) lifted Occupancy 16->29% and gave the
// first real gain after three null schedule rewrites -> occupancy is the
// lever at this shape. This round: 2-deep LDS (48 KiB) -> 3 blocks/CU
// (__launch_bounds__(512,6); R6 VGPR=60 <= 85). The per-tile vmcnt(0) drain
// this reintroduces is covered by the two co-resident blocks (the R6 lesson);
// staging for t+1 is issued at the TOP of tile t so the loads have the whole
// MFMA phase to land. Race-safe: stage targets buf^1, released by all waves
// at the previous boundary's lgkm(0)+barrier.
// Swizzle (BK=32, unchanged from R6): unit(row,chunk) = row*4 +
// (chunk ^ ((row ^ row>>2) & 3)), applied on the GLOBAL side of
// global_load_lds (LDS dest stays linear per the wave-uniform-base rule).
template <int EPI, typename CT>
__device__ __forceinline__
void gemm_tile(const bf16_t* __restrict__ A, const bf16_t* __restrict__ B,
               CT* __restrict__ C, const float* __restrict__ bias,
               int m0, int n0, int N, int K,
               bf16_t* __restrict__ As, bf16_t* __restrict__ Bs)
{
    const int lane = threadIdx.x & 63;
    const int wave = threadIdx.x >> 6;   // 0..7
    const int wm = wave >> 1;            // 0..3: 64-row band of A
    const int wn = wave & 1;             // 0..1: 64-col band of B

    const int fm   = lane & 15;
    const int q    = lane >> 4;          // 0..3 = k-chunk of the fragment
    const int fsw2 = (fm ^ (fm >> 2)) & 3;

    const int NT = K / BK;               // 24 for K=768

    // staging: per K-tile each wave issues 3 global_load_lds (2 A + 1 B),
    // each 64 lanes x 16B = 1 KiB.
    const bf16_t* ga0; const bf16_t* ga1; const bf16_t* gb;
    {
        const int u0 = (wave * 2) * 64 + lane;
        const int r0 = u0 >> 2;
        ga0 = A + (size_t)(m0 + r0) * K + (((u0 & 3) ^ ((r0 ^ (r0 >> 2)) & 3)) * 8);
        const int u1 = (wave * 2 + 1) * 64 + lane;
        const int r1 = u1 >> 2;
        ga1 = A + (size_t)(m0 + r1) * K + (((u1 & 3) ^ ((r1 ^ (r1 >> 2)) & 3)) * 8);
        const int ub = wave * 64 + lane;
        const int rb = ub >> 2;
        gb  = B + (size_t)(n0 + rb) * K + (((ub & 3) ^ ((rb ^ (rb >> 2)) & 3)) * 8);
    }
    const int la0 = wave * 1024;         // elem offsets (unit*8), wave-uniform
    const int la1 = wave * 1024 + 512;
    const int lb  = wave * 512;

#define STAGE(tt, Ad, Bd) do {                                   \
    GLD16(ga0 + (size_t)(tt) * BK, (Ad) + la0);                  \
    GLD16(ga1 + (size_t)(tt) * BK, (Ad) + la1);                  \
    GLD16(gb  + (size_t)(tt) * BK, (Bd) + lb);                   \
} while (0)

    f32x4 acc[4][4];
#pragma unroll
    for (int i = 0; i < 4; ++i)
#pragma unroll
        for (int j = 0; j < 4; ++j) acc[i][j] = (f32x4){0.f, 0.f, 0.f, 0.f};

    // prologue: stage tile 0 -> buf0
    STAGE(0, As, Bs);
    asm volatile("s_waitcnt vmcnt(0)" ::: "memory");
    blockbar();

    for (int t = 0; t < NT; ++t) {
        const bf16_t* __restrict__ Ab = As + (t & 1) * ABUF;
        const bf16_t* __restrict__ Bb = Bs + (t & 1) * BBUF;

        // issue next-tile staging FIRST: full MFMA phase covers the latency
        if (t + 1 < NT)
            STAGE(t + 1, As + ((t + 1) & 1) * ABUF, Bs + ((t + 1) & 1) * BBUF);

        bf16x8 af[4], bfr[4];
#pragma unroll
        for (int i = 0; i < 4; ++i) {
            const int row = wm * 64 + i * 16 + fm;
            af[i] = *(const bf16x8*)(Ab + (size_t)(row * 4 + (q ^ fsw2)) * 8);
        }
#pragma unroll
        for (int j = 0; j < 4; ++j) {
            const int row = wn * 64 + j * 16 + fm;
            bfr[j] = *(const bf16x8*)(Bb + (size_t)(row * 4 + (q ^ fsw2)) * 8);
        }

        __builtin_amdgcn_s_setprio(1);
#pragma unroll
        for (int i = 0; i < 4; ++i)
#pragma unroll
            for (int j = 0; j < 4; ++j)
                acc[i][j] = __builtin_amdgcn_mfma_f32_16x16x32_bf16(
                    af[i], bfr[j], acc[i][j], 0, 0, 0);
        __builtin_amdgcn_s_setprio(0);

        if (t < NT - 1) {
            // all frag reads of the buffer staging will overwrite retired;
            // tile t+1 fully landed (drain covered by co-resident blocks)
            asm volatile("s_waitcnt lgkmcnt(0)" ::: "memory");
            asm volatile("s_waitcnt vmcnt(0)" ::: "memory");
            blockbar();
        }
    }

    // epilogue: C/D layout col=lane&15, row=q*4+r
#pragma unroll
    for (int i = 0; i < 4; ++i) {
#pragma unroll
        for (int j = 0; j < 4; ++j) {
            const int col = n0 + wn * 64 + j * 16 + fm;
            float bv = 0.f;
            if (EPI == EPI_BIAS) bv = bias[col];
#pragma unroll
            for (int r = 0; r < 4; ++r) {
                const int row = m0 + wm * 64 + i * 16 + q * 4 + r;
                float v = acc[i][j][r];
                if (EPI == EPI_THRESH) v = (fabsf(v) > 1e-3f) ? v : 0.f;
                if (EPI == EPI_BIAS) v += bv;
                C[(size_t)row * N + col] = (CT)v;
            }
        }
    }
#undef STAGE
}

// dispatch 2: blocks 0..17 = Wc = VTb @ Wt^T (front, absorbed by
// co-residency); blocks 18..785 = h = thresh(xb @ Ub^T), bijective XCD
// swizzle over 768 (768%8==0).
__global__ __launch_bounds__(512, 6)
void gemm_h_wc(const bf16_t* __restrict__ xb, const bf16_t* __restrict__ Ub,
               bf16_t* __restrict__ h,
               const bf16_t* __restrict__ VTb, const bf16_t* __restrict__ Wt,
               bf16_t* __restrict__ Wc)
{
    __shared__ __align__(16) bf16_t As[2 * ABUF];   // 32 KiB
    __shared__ __align__(16) bf16_t Bs[2 * BBUF];   // 16 KiB
    const int b = blockIdx.x;
    if (b < 18) {
        gemm_tile<EPI_NONE, bf16_t>(VTb, Wt, Wc, nullptr,
                                    (b / 6) * BM, (b % 6) * BN, 768, 768, As, Bs);
    } else {
        const int bb = b - 18;
        const int L = (bb & 7) * 96 + (bb >> 3);    // XCD-contiguous tiles
        gemm_tile<EPI_THRESH, bf16_t>(xb, Ub, h, nullptr,
                                      (L / 6) * BM, (L % 6) * BN, 768, 768, As, Bs);
    }
}

// dispatch 3: out = h @ Wc^T + bias (fp32 store)
__global__ __launch_bounds__(512, 6)
void gemm_out(const bf16_t* __restrict__ h, const bf16_t* __restrict__ Wc,
              float* __restrict__ out, const float* __restrict__ bias)
{
    __shared__ __align__(16) bf16_t As[2 * ABUF];
    __shared__ __align__(16) bf16_t Bs[2 * BBUF];
    const int b = blockIdx.x;
    const int L = (b & 7) * 96 + (b >> 3);
    gemm_tile<EPI_BIAS, float>(h, Wc, out, bias,
                               (L / 6) * BM, (L % 6) * BN, 768, 768, As, Bs);
}

// dispatch 1: fp32->bf16 conversions + weight transpose (R6 version: x IS
// converted here -- the fused-conversion variants measured worse).
// blocks [0,12288): x; [12288,12576): U; [12576,12864): VT; [12864,13440): w^T
__global__ __launch_bounds__(256)
void prep(const float* __restrict__ x, const float* __restrict__ U,
          const float* __restrict__ VT, const float* __restrict__ w,
          bf16_t* __restrict__ xb, bf16_t* __restrict__ Ub,
          bf16_t* __restrict__ VTb, bf16_t* __restrict__ Wt)
{
    __shared__ float tt[32][33];
    const int b = blockIdx.x;
    if (b < 12864) {
        const float* src; bf16_t* dst; size_t e;
        if (b < 12288)      { src = x;  dst = xb;  e = (size_t)b * 2048; }
        else if (b < 12576) { src = U;  dst = Ub;  e = (size_t)(b - 12288) * 2048; }
        else                { src = VT; dst = VTb; e = (size_t)(b - 12576) * 2048; }
        const size_t i = e + (size_t)threadIdx.x * 8;
        const f32x4 v0 = *(const f32x4*)(src + i);
        const f32x4 v1 = *(const f32x4*)(src + i + 4);
        bf16x8 o;
        o[0] = (bf16_t)v0[0]; o[1] = (bf16_t)v0[1];
        o[2] = (bf16_t)v0[2]; o[3] = (bf16_t)v0[3];
        o[4] = (bf16_t)v1[0]; o[5] = (bf16_t)v1[1];
        o[6] = (bf16_t)v1[2]; o[7] = (bf16_t)v1[3];
        *(bf16x8*)(dst + i) = o;
    } else {
        const int t = b - 12864;              // 0..575
        const int bx = (t % 24) * 32, by = (t / 24) * 32;
        const int tx = threadIdx.x & 31, ty = threadIdx.x >> 5;  // 32 x 8
#pragma unroll
        for (int i = 0; i < 32; i += 8)
            tt[ty + i][tx] = w[(size_t)(by + ty + i) * 768 + bx + tx];
        __syncthreads();
#pragma unroll
        for (int i = 0; i < 32; i += 8)
            Wt[(size_t)(bx + ty + i) * 768 + by + tx] = (bf16_t)tt[tx][ty + i];
    }
}

extern "C" void kernel_launch(void* const* d_in, const int* in_sizes, int n_in,
                              void* d_out, int out_size, void* d_ws, size_t ws_size,
                              hipStream_t stream)
{
    const float* x    = (const float*)d_in[0];   // (8,4096,768) fp32
    const float* w    = (const float*)d_in[1];   // (768,768) fp32
    const float* bias = (const float*)d_in[2];   // (768,) fp32
    const float* U    = (const float*)d_in[3];   // (768,768) fp32
    const float* VT   = (const float*)d_in[4];   // (768,768) fp32
    float* out = (float*)d_out;                  // (8,4096,768) fp32

    const int D = 768;
    const int M = 8 * 4096;                      // 32768
    const size_t MD = (size_t)M * D;
    const size_t DD = (size_t)D * D;

    char* ws = (char*)d_ws;
    bf16_t* xb  = (bf16_t*)ws;                         // MD bf16
    bf16_t* h   = (bf16_t*)(ws + MD * 2);              // MD bf16
    bf16_t* Ub  = (bf16_t*)(ws + MD * 4);              // DD
    bf16_t* VTb = (bf16_t*)(ws + MD * 4 + DD * 2);     // DD
    bf16_t* Wt  = (bf16_t*)(ws + MD * 4 + DD * 4);     // DD: weight^T
    bf16_t* Wc  = (bf16_t*)(ws + MD * 4 + DD * 6);     // DD: VT@weight

    // 1) conversions + transpose fused
    prep<<<13440, 256, 0, stream>>>(x, U, VT, w, xb, Ub, VTb, Wt);
    // 2) Wc = (VT @ weight) [first 18 blocks] + h = thresh(xb @ Ub^T)
    gemm_h_wc<<<18 + 768, 512, 0, stream>>>(xb, Ub, h, VTb, Wt, Wc);
    // 3) out = h @ Wc^T + bias  (== ((h @ W^T) @ VT^T) + bias)
    gemm_out<<<768, 512, 0, stream>>>(h, Wc, out, bias);
}

// Round 10
// 298.845 us; speedup vs baseline: 2.8347x; 2.8347x over previous
//
#include <hip/hip_runtime.h>
#include <hip/hip_bf16.h>

typedef __bf16 bf16_t;
typedef bf16_t bf16x8 __attribute__((ext_vector_type(8)));
typedef bf16_t bf16x4 __attribute__((ext_vector_type(4)));
typedef float  f32x4  __attribute__((ext_vector_type(4)));

#define BM 128
#define BN 128
#define BK 32            // one K-tile; a row is 4 chunks of 8 bf16 (16B each)
#define ABUF (BM * BK)   // 4096 elems
#define BBUF (BN * BK)   // 4096 elems

enum { EPI_NONE = 0, EPI_THRESH = 1, EPI_BIAS = 2 };

__device__ __forceinline__ void memfence() { asm volatile("" ::: "memory"); }
__device__ __forceinline__ void blockbar() {
    memfence(); __builtin_amdgcn_s_barrier(); memfence();
}

#define GLD16(src, dst) __builtin_amdgcn_global_load_lds( \
    (const __attribute__((address_space(1))) void*)(src), \
    (__attribute__((address_space(3))) void*)(dst), 16, 0, 0)

// 128x128 tile, BK=32, 512 threads = 8 waves (4M x 2N), per-wave C = 32x64.
// REGISTER MATH (the R9 lesson -- AGPRs share the unified file):
//   acc 2x4 f32x4 = 32 AGPR; arch VGPR ~45 -> ~77 total <= 2048/24 = 85
//   => 24 waves/CU (3 blocks) WITHOUT accumulator spill. R9's 64-AGPR acc at
//   a 24-wave budget spilled to scratch (WRITE_SIZE 960 MB, 6x regression).
// 2-deep LDS (32 KiB -> 3 blocks = 96 KiB <= 160): stage t+1 issued at the
// TOP of tile t (full MFMA phase covers latency); per-tile vmcnt(0) drain is
// covered by the two co-resident blocks (R6's measured lesson: occupancy is
// the lever at this shape, not schedule).
// Swizzle (BK=32, R6-proven): unit(row,chunk) = row*4 +
// (chunk ^ ((row ^ row>>2) & 3)), applied on the GLOBAL side of
// global_load_lds (LDS dest stays linear per the wave-uniform-base rule).
template <int EPI, typename CT>
__device__ __forceinline__
void gemm_tile(const bf16_t* __restrict__ A, const bf16_t* __restrict__ B,
               CT* __restrict__ C, const float* __restrict__ bias,
               int m0, int n0, int N, int K,
               bf16_t* __restrict__ As, bf16_t* __restrict__ Bs)
{
    const int lane = threadIdx.x & 63;
    const int wave = threadIdx.x >> 6;   // 0..7
    const int wm = wave >> 1;            // 0..3: 32-row band of A
    const int wn = wave & 1;             // 0..1: 64-col band of B

    const int fm   = lane & 15;
    const int q    = lane >> 4;          // 0..3 = k-chunk of the fragment
    const int fsw2 = (fm ^ (fm >> 2)) & 3;

    const int NT = K / BK;               // 24 for K=768

    // staging: per K-tile each wave issues 2 global_load_lds (1 A + 1 B),
    // each 64 lanes x 16B = 1 KiB. A: 512 units (128 rows x 4 chunks);
    // wave w covers units w*64+lane -> rows [w*16, w*16+16). B identical.
    const bf16_t* ga; const bf16_t* gb;
    {
        const int ua = wave * 64 + lane;
        const int ra = ua >> 2;
        ga = A + (size_t)(m0 + ra) * K + (((ua & 3) ^ ((ra ^ (ra >> 2)) & 3)) * 8);
        const int ub = wave * 64 + lane;
        const int rb = ub >> 2;
        gb = B + (size_t)(n0 + rb) * K + (((ub & 3) ^ ((rb ^ (rb >> 2)) & 3)) * 8);
    }
    const int la = wave * 512;           // elem offsets (unit*8), wave-uniform
    const int lb = wave * 512;

#define STAGE(tt, Ad, Bd) do {                                   \
    GLD16(ga + (size_t)(tt) * BK, (Ad) + la);                    \
    GLD16(gb + (size_t)(tt) * BK, (Bd) + lb);                    \
} while (0)

    f32x4 acc[2][4];
#pragma unroll
    for (int i = 0; i < 2; ++i)
#pragma unroll
        for (int j = 0; j < 4; ++j) acc[i][j] = (f32x4){0.f, 0.f, 0.f, 0.f};

    // prologue: stage tile 0 -> buf0
    STAGE(0, As, Bs);
    asm volatile("s_waitcnt vmcnt(0)" ::: "memory");
    blockbar();

    for (int t = 0; t < NT; ++t) {
        const bf16_t* __restrict__ Ab = As + (t & 1) * ABUF;
        const bf16_t* __restrict__ Bb = Bs + (t & 1) * BBUF;

        // issue next-tile staging FIRST: full MFMA phase covers the latency
        if (t + 1 < NT)
            STAGE(t + 1, As + ((t + 1) & 1) * ABUF, Bs + ((t + 1) & 1) * BBUF);

        bf16x8 af[2], bfr[4];
#pragma unroll
        for (int i = 0; i < 2; ++i) {
            const int row = wm * 32 + i * 16 + fm;
            af[i] = *(const bf16x8*)(Ab + (size_t)(row * 4 + (q ^ fsw2)) * 8);
        }
#pragma unroll
        for (int j = 0; j < 4; ++j) {
            const int row = wn * 64 + j * 16 + fm;
            bfr[j] = *(const bf16x8*)(Bb + (size_t)(row * 4 + (q ^ fsw2)) * 8);
        }

        __builtin_amdgcn_s_setprio(1);
#pragma unroll
        for (int i = 0; i < 2; ++i)
#pragma unroll
            for (int j = 0; j < 4; ++j)
                acc[i][j] = __builtin_amdgcn_mfma_f32_16x16x32_bf16(
                    af[i], bfr[j], acc[i][j], 0, 0, 0);
        __builtin_amdgcn_s_setprio(0);

        if (t < NT - 1) {
            // frag reads of the to-be-overwritten buffer retired; tile t+1
            // landed (drain covered by the 2 co-resident blocks)
            asm volatile("s_waitcnt lgkmcnt(0)" ::: "memory");
            asm volatile("s_waitcnt vmcnt(0)" ::: "memory");
            blockbar();
        }
    }

    // epilogue: C/D layout col=lane&15, row=q*4+r
#pragma unroll
    for (int i = 0; i < 2; ++i) {
#pragma unroll
        for (int j = 0; j < 4; ++j) {
            const int col = n0 + wn * 64 + j * 16 + fm;
            float bv = 0.f;
            if (EPI == EPI_BIAS) bv = bias[col];
#pragma unroll
            for (int r = 0; r < 4; ++r) {
                const int row = m0 + wm * 32 + i * 16 + q * 4 + r;
                float v = acc[i][j][r];
                if (EPI == EPI_THRESH) v = (fabsf(v) > 1e-3f) ? v : 0.f;
                if (EPI == EPI_BIAS) v += bv;
                C[(size_t)row * N + col] = (CT)v;
            }
        }
    }
#undef STAGE
}

// dispatch 2: blocks 0..35 = Wc = VTb @ Wt^T (6x6 tiles of 128x128, front-
// loaded, absorbed by co-residency); blocks 36..1571 = h = thresh(xb @ Ub^T),
// bijective XCD swizzle over 1536 (1536%8==0; 2 exact rounds at 3 blocks/CU).
__global__ __launch_bounds__(512, 6)
void gemm_h_wc(const bf16_t* __restrict__ xb, const bf16_t* __restrict__ Ub,
               bf16_t* __restrict__ h,
               const bf16_t* __restrict__ VTb, const bf16_t* __restrict__ Wt,
               bf16_t* __restrict__ Wc)
{
    __shared__ __align__(16) bf16_t As[2 * ABUF];   // 16 KiB
    __shared__ __align__(16) bf16_t Bs[2 * BBUF];   // 16 KiB
    const int b = blockIdx.x;
    if (b < 36) {
        gemm_tile<EPI_NONE, bf16_t>(VTb, Wt, Wc, nullptr,
                                    (b / 6) * BM, (b % 6) * BN, 768, 768, As, Bs);
    } else {
        const int bb = b - 36;
        const int L = (bb & 7) * 192 + (bb >> 3);   // XCD-contiguous tiles
        gemm_tile<EPI_THRESH, bf16_t>(xb, Ub, h, nullptr,
                                      (L / 6) * BM, (L % 6) * BN, 768, 768, As, Bs);
    }
}

// dispatch 3: out = h @ Wc^T + bias (fp32 store)
__global__ __launch_bounds__(512, 6)
void gemm_out(const bf16_t* __restrict__ h, const bf16_t* __restrict__ Wc,
              float* __restrict__ out, const float* __restrict__ bias)
{
    __shared__ __align__(16) bf16_t As[2 * ABUF];
    __shared__ __align__(16) bf16_t Bs[2 * BBUF];
    const int b = blockIdx.x;
    const int L = (b & 7) * 192 + (b >> 3);
    gemm_tile<EPI_BIAS, float>(h, Wc, out, bias,
                               (L / 6) * BM, (L % 6) * BN, 768, 768, As, Bs);
}

// dispatch 1: fp32->bf16 conversions + weight transpose (R6 version, proven).
// blocks [0,12288): x; [12288,12576): U; [12576,12864): VT; [12864,13440): w^T
__global__ __launch_bounds__(256)
void prep(const float* __restrict__ x, const float* __restrict__ U,
          const float* __restrict__ VT, const float* __restrict__ w,
          bf16_t* __restrict__ xb, bf16_t* __restrict__ Ub,
          bf16_t* __restrict__ VTb, bf16_t* __restrict__ Wt)
{
    __shared__ float tt[32][33];
    const int b = blockIdx.x;
    if (b < 12864) {
        const float* src; bf16_t* dst; size_t e;
        if (b < 12288)      { src = x;  dst = xb;  e = (size_t)b * 2048; }
        else if (b < 12576) { src = U;  dst = Ub;  e = (size_t)(b - 12288) * 2048; }
        else                { src = VT; dst = VTb; e = (size_t)(b - 12576) * 2048; }
        const size_t i = e + (size_t)threadIdx.x * 8;
        const f32x4 v0 = *(const f32x4*)(src + i);
        const f32x4 v1 = *(const f32x4*)(src + i + 4);
        bf16x8 o;
        o[0] = (bf16_t)v0[0]; o[1] = (bf16_t)v0[1];
        o[2] = (bf16_t)v0[2]; o[3] = (bf16_t)v0[3];
        o[4] = (bf16_t)v1[0]; o[5] = (bf16_t)v1[1];
        o[6] = (bf16_t)v1[2]; o[7] = (bf16_t)v1[3];
        *(bf16x8*)(dst + i) = o;
    } else {
        const int t = b - 12864;              // 0..575
        const int bx = (t % 24) * 32, by = (t / 24) * 32;
        const int tx = threadIdx.x & 31, ty = threadIdx.x >> 5;  // 32 x 8
#pragma unroll
        for (int i = 0; i < 32; i += 8)
            tt[ty + i][tx] = w[(size_t)(by + ty + i) * 768 + bx + tx];
        __syncthreads();
#pragma unroll
        for (int i = 0; i < 32; i += 8)
            Wt[(size_t)(bx + ty + i) * 768 + by + tx] = (bf16_t)tt[tx][ty + i];
    }
}

extern "C" void kernel_launch(void* const* d_in, const int* in_sizes, int n_in,
                              void* d_out, int out_size, void* d_ws, size_t ws_size,
                              hipStream_t stream)
{
    const float* x    = (const float*)d_in[0];   // (8,4096,768) fp32
    const float* w    = (const float*)d_in[1];   // (768,768) fp32
    const float* bias = (const float*)d_in[2];   // (768,) fp32
    const float* U    = (const float*)d_in[3];   // (768,768) fp32
    const float* VT   = (const float*)d_in[4];   // (768,768) fp32
    float* out = (float*)d_out;                  // (8,4096,768) fp32

    const int D = 768;
    const int M = 8 * 4096;                      // 32768
    const size_t MD = (size_t)M * D;
    const size_t DD = (size_t)D * D;

    char* ws = (char*)d_ws;
    bf16_t* xb  = (bf16_t*)ws;                         // MD bf16
    bf16_t* h   = (bf16_t*)(ws + MD * 2);              // MD bf16
    bf16_t* Ub  = (bf16_t*)(ws + MD * 4);              // DD
    bf16_t* VTb = (bf16_t*)(ws + MD * 4 + DD * 2);     // DD
    bf16_t* Wt  = (bf16_t*)(ws + MD * 4 + DD * 4);     // DD: weight^T
    bf16_t* Wc  = (bf16_t*)(ws + MD * 4 + DD * 6);     // DD: VT@weight

    // 1) conversions + transpose fused
    prep<<<13440, 256, 0, stream>>>(x, U, VT, w, xb, Ub, VTb, Wt);
    // 2) Wc = (VT @ weight) [first 36 blocks] + h = thresh(xb @ Ub^T)
    gemm_h_wc<<<36 + 1536, 512, 0, stream>>>(xb, Ub, h, VTb, Wt, Wc);
    // 3) out = h @ Wc^T + bias  (== ((h @ W^T) @ VT^T) + bias)
    gemm_out<<<1536, 512, 0, stream>>>(h, Wc, out, bias);
}